// Round 10
// baseline (43.876 us; speedup 1.0000x reference)
//
#include <hip/hip_runtime.h>
#include <math.h>

#define HH 320
#define WW 320
#define HWP (HH * WW)       // pixels per batch image
#define KTOP 80
#define CNT_STRIDE 64       // pad per-batch counters to separate 256B lines
#define CAP (HWP / 2)       // max candidates kept per batch (val+idx pack one buffer)
#define LVCAP 8192          // candidates cached in LDS for topk (32KB)
#define TW 32               // pool/nms tile width
#define TH 64               // pool/nms tile height
#define NTPRX (WW / TW)     // 10 tiles per row
#define NTPI (NTPRX * (HH / TH))  // 50 tiles per image
#define GSW 64              // gauss strip width
#define GSH 16              // gauss strip height
#define SPRX (WW / GSW)     // 5 strips per row
#define SPI (SPRX * (HH / GSH))  // 100 strips per image
#define LOG2E 1.4426950408889634f
#define NLOG2TAU 19.931568569324174f   // -log2(1e-6)

// Agent-scope coherent access: sc0/sc1 write-through to the coherence point —
// device-visible WITHOUT any L2 writeback fence (the R7 failure mechanism).
#define STORE_COH(p, v) __hip_atomic_store((p), (v), __ATOMIC_RELAXED, __HIP_MEMORY_SCOPE_AGENT)
#define LOAD_COH(p)     __hip_atomic_load((p), __ATOMIC_RELAXED, __HIP_MEMORY_SCOPE_AGENT)

__device__ __forceinline__ void wave_minmax(float& mn, float& mx) {
    for (int off = 32; off > 0; off >>= 1) {
        mn = fminf(mn, __shfl_xor(mn, off, 64));
        mx = fmaxf(mx, __shfl_xor(mx, off, 64));
    }
}

// ---- K1: fused 9x9 avg pools -> prod, per-block minmax -> pmm ---------------
__global__ __launch_bounds__(256) void pool_fused_k(
        const float* __restrict__ score, float* __restrict__ prod,
        float2* __restrict__ pmm, int* __restrict__ cand_cnt,
        int* __restrict__ done_cnt, int B_) {
    int tid = threadIdx.x;
    if (blockIdx.x == 0)
        for (int t = tid; t < B_ * CNT_STRIDE; t += 256) { cand_cnt[t] = 0; done_cnt[t] = 0; }
    int blk = blockIdx.x;
    int b = blk / NTPI, t = blk % NTPI;
    int ty0 = (t / NTPRX) * TH, tx0 = (t % NTPRX) * TW;
    __shared__ float rss[TH + 8][TW + 4];   // [72][36], row sums (score)
    __shared__ float rso[TH + 8][TW + 4];   // [72][36], row sums (occ)
    const float4* img4 = (const float4*)(score + b * HWP);
    // phase A: 9-tap row sums for 72 rows x 8 quads (zero-pad OOB)
    for (int i = tid; i < (TH + 8) * (TW / 4); i += 256) {
        int r = i / (TW / 4), q = i % (TW / 4);
        int gy = ty0 - 4 + r;
        float o0=0,o1=0,o2=0,o3=0,p0=0,p1=0,p2=0,p3=0;
        if (gy >= 0 && gy < HH) {
            const float4* row4 = img4 + gy * (WW / 4);
            int gq = tx0 / 4 + q;
            float4 a = (gq > 0) ? row4[gq - 1] : make_float4(0,0,0,0);
            float4 bb = row4[gq];
            float4 c = (gq < WW / 4 - 1) ? row4[gq + 1] : make_float4(0,0,0,0);
            float w0=a.x,w1=a.y,w2=a.z,w3=a.w,w4=bb.x,w5=bb.y,w6=bb.z,w7=bb.w,w8=c.x,w9=c.y,w10=c.z,w11=c.w;
            float s = w0+w1+w2+w3+w4+w5+w6+w7+w8;
            o0=s; s+=w9-w0; o1=s; s+=w10-w1; o2=s; s+=w11-w2; o3=s;
            float c0=(w0>0.2f)?1.f:0.f, c1=(w1>0.2f)?1.f:0.f, c2=(w2>0.2f)?1.f:0.f, c3=(w3>0.2f)?1.f:0.f;
            float c4=(w4>0.2f)?1.f:0.f, c5=(w5>0.2f)?1.f:0.f, c6=(w6>0.2f)?1.f:0.f, c7=(w7>0.2f)?1.f:0.f;
            float c8=(w8>0.2f)?1.f:0.f, c9=(w9>0.2f)?1.f:0.f, c10=(w10>0.2f)?1.f:0.f, c11=(w11>0.2f)?1.f:0.f;
            float u = c0+c1+c2+c3+c4+c5+c6+c7+c8;
            p0=u; u+=c9-c0; p1=u; u+=c10-c1; p2=u; u+=c11-c2; p3=u;
        }
        *(float4*)&rss[r][q * 4] = make_float4(o0,o1,o2,o3);
        *(float4*)&rso[r][q * 4] = make_float4(p0,p1,p2,p3);
    }
    __syncthreads();
    // phase B: 9-tap column sums -> prod + minmax
    float tmn = INFINITY, tmx = 0.f;
    const float inv81 = 1.0f / 81.0f;
    float4* pr4 = (float4*)(prod + b * HWP);
    for (int i = tid; i < TH * (TW / 4); i += 256) {
        int r = i / (TW / 4), q = i % (TW / 4);
        float sx=0,sy=0,sz=0,sw=0, ox=0,oy=0,oz=0,ow=0;
#pragma unroll
        for (int j = 0; j < 9; ++j) {
            float4 s = *(float4*)&rss[r + j][q * 4];
            float4 o = *(float4*)&rso[r + j][q * 4];
            sx+=s.x; sy+=s.y; sz+=s.z; sw+=s.w;
            ox+=o.x; oy+=o.y; oz+=o.z; ow+=o.w;
        }
        float px=(ox*inv81)*(sx*inv81), py=(oy*inv81)*(sy*inv81);
        float pz=(oz*inv81)*(sz*inv81), pw=(ow*inv81)*(sw*inv81);
        pr4[(ty0 + r) * (WW / 4) + tx0 / 4 + q] = make_float4(px,py,pz,pw);
        tmn = fminf(tmn, fminf(fminf(px,py), fminf(pz,pw)));
        tmx = fmaxf(tmx, fmaxf(fmaxf(px,py), fmaxf(pz,pw)));
    }
    wave_minmax(tmn, tmx);
    __shared__ float wmn[4], wmx[4];
    int w = tid >> 6;
    if ((tid & 63) == 0) { wmn[w] = tmn; wmx[w] = tmx; }
    __syncthreads();
    if (tid == 0)
        pmm[blk] = make_float2(fminf(fminf(wmn[0],wmn[1]), fminf(wmn[2],wmn[3])),
                               fmaxf(fmaxf(wmx[0],wmx[1]), fmaxf(wmx[2],wmx[3])));
}

// ---- K2: compact_score + 5x5 NMS + compaction; last-done block: topk --------
__global__ __launch_bounds__(256) void cs_nms_topk_k(
        const float* __restrict__ score, const float* __restrict__ prod,
        const float2* __restrict__ pmm, float* __restrict__ cand_base,
        int* __restrict__ cand_cnt, int* __restrict__ done_cnt,
        const float* __restrict__ depth, float4* __restrict__ pk4g) {
    int tid = threadIdx.x;
    int blk = blockIdx.x;
    int b = blk / NTPI, t = blk % NTPI;
    int ty0 = (t / NTPRX) * TH, tx0 = (t % NTPRX) * TW;
    // reduce this batch's NTPI pmm pairs (wave 0 does the work)
    float tmn = INFINITY, tmx = 0.f;
    if (tid < NTPI) { float2 e = pmm[b * NTPI + tid]; tmn = e.x; tmx = e.y; }
    wave_minmax(tmn, tmx);
    __shared__ float s_mn, s_inv;
    if (tid == 0) { s_mn = tmn; s_inv = 1.0f / (tmx - tmn + 1e-6f); }
    __shared__ float cs[TH + 4][TW + 8 + 4];   // [68][44], col 0 <-> gx = tx0-4
    __shared__ float rm[TH + 4][TW + 4];       // [68][36], 5-tap row max
    __syncthreads();
    float mn = s_mn, inv = s_inv;
    const float4* sc4 = (const float4*)(score + b * HWP);
    const float4* pr4 = (const float4*)(prod + b * HWP);
    // phase A: cs over rows ty0-2..+65, 10 col quads (zero-pad OOB)
    for (int i = tid; i < (TH + 4) * 10; i += 256) {
        int r = i / 10, q = i % 10;
        int gy = ty0 - 2 + r;
        int gq = tx0 / 4 - 1 + q;
        float4 c4 = make_float4(0,0,0,0);
        if (gy >= 0 && gy < HH && gq >= 0 && gq < WW / 4) {
            float4 s4 = sc4[gy * (WW / 4) + gq];
            float4 p4 = pr4[gy * (WW / 4) + gq];
            c4.x = s4.x * ((p4.x - mn) * inv); c4.y = s4.y * ((p4.y - mn) * inv);
            c4.z = s4.z * ((p4.z - mn) * inv); c4.w = s4.w * ((p4.w - mn) * inv);
        }
        *(float4*)&cs[r][q * 4] = c4;
    }
    __syncthreads();
    // phase B: rm[r][x] = max cs[r][x+2 .. x+6]  (px col x <-> cs col x+4)
    for (int i = tid; i < (TH + 4) * (TW / 4); i += 256) {
        int r = i / (TW / 4), x = (i % (TW / 4)) * 4;
        float c0=cs[r][x+2], c1=cs[r][x+3], c2=cs[r][x+4], c3=cs[r][x+5];
        float c4v=cs[r][x+6], c5=cs[r][x+7], c6=cs[r][x+8], c7=cs[r][x+9];
        float m01=fmaxf(c0,c1), m23=fmaxf(c2,c3), m45=fmaxf(c4v,c5), m67=fmaxf(c6,c7);
        float r0 = fmaxf(fmaxf(m01, m23), c4v);
        float r1 = fmaxf(fmaxf(c1, m23), m45);
        float r2 = fmaxf(fmaxf(m23, m45), c6);
        float r3 = fmaxf(fmaxf(c3, m45), m67);
        *(float4*)&rm[r][x] = make_float4(r0,r1,r2,r3);
    }
    __syncthreads();
    // phase C: NMS decision, 2 quads/thread (512 quads = 2*256 exactly)
    bool cd[8]; float vv[8]; int pb[2]; int offs[8];
#pragma unroll
    for (int qq = 0; qq < 2; ++qq) {
        int quad = qq * 256 + tid;
        int r = quad >> 3, x = (quad & 7) * 4;
        float4 v = *(float4*)&cs[r + 2][x + 4];
        float4 nm = *(float4*)&rm[r][x];
#pragma unroll
        for (int k = 1; k <= 4; ++k) {
            float4 rr = *(float4*)&rm[r + k][x];
            nm.x=fmaxf(nm.x,rr.x); nm.y=fmaxf(nm.y,rr.y);
            nm.z=fmaxf(nm.z,rr.z); nm.w=fmaxf(nm.w,rr.w);
        }
        pb[qq] = (ty0 + r) * WW + tx0 + x;
        cd[qq*4+0] = v.x > 0.f && v.x >= nm.x; vv[qq*4+0] = v.x;
        cd[qq*4+1] = v.y > 0.f && v.y >= nm.y; vv[qq*4+1] = v.y;
        cd[qq*4+2] = v.z > 0.f && v.z >= nm.z; vv[qq*4+2] = v.z;
        cd[qq*4+3] = v.w > 0.f && v.w >= nm.w; vv[qq*4+3] = v.w;
    }
    int lane = tid & 63, w = tid >> 6;
    unsigned long long lower = (1ULL << lane) - 1ULL;
    int wave_run = 0;
#pragma unroll
    for (int j = 0; j < 8; ++j) {
        unsigned long long m = __ballot(cd[j]);
        offs[j] = wave_run + __popcll(m & lower);
        wave_run += __popcll(m);
    }
    __shared__ int wbase[4];
    __shared__ int blockbase;
    if (lane == 0) wbase[w] = wave_run;
    __syncthreads();
    if (tid == 0) {
        int a0=wbase[0], a1=wbase[1], a2=wbase[2], a3=wbase[3];
        int tot = a0+a1+a2+a3;
        wbase[0]=0; wbase[1]=a0; wbase[2]=a0+a1; wbase[3]=a0+a1+a2;
        blockbase = tot ? atomicAdd(&cand_cnt[b * CNT_STRIDE], tot) : 0;
    }
    __syncthreads();
    float* cv_w = cand_base + b * HWP;
    int* ci_w = (int*)(cand_base + b * HWP + CAP);
    int bb2 = blockbase + wbase[w];
#pragma unroll
    for (int j = 0; j < 8; ++j) {
        if (cd[j]) {
            int slot = bb2 + offs[j];
            if (slot < CAP) {
                STORE_COH(&cv_w[slot], vv[j]);              // device-coherent write-through
                STORE_COH(&ci_w[slot], pb[j >> 2] + (j & 3));
            }
        }
    }
    // ---- last-done block of this batch runs topk inline (NO fences) ---------
    asm volatile("s_waitcnt vmcnt(0)" ::: "memory");  // this wave's stores acked at coherence point
    __syncthreads();                                  // all waves drained (barrier implies vmcnt(0))
    __shared__ int s_last;
    if (tid == 0) s_last = atomicAdd(&done_cnt[b * CNT_STRIDE], 1);
    __syncthreads();
    if (s_last != NTPI - 1) return;

    int n = atomicAdd(&cand_cnt[b * CNT_STRIDE], 0);  // coherent read of final count
    if (n > CAP) n = CAP;
    const float* cv = cand_base + b * HWP;
    const int* ci = (const int*)(cand_base + b * HWP + CAP);

    __shared__ float cvl[LVCAP];
    __shared__ int hist[256];
    __shared__ unsigned s_prefix;
    __shared__ int s_kth;
    __shared__ float sel_v[KTOP];
    __shared__ int sel_i[KTOP];
    __shared__ int s_ng, s_nt;
    __shared__ int tie_i[512];
    __shared__ float s_lvoff;

    bool inl = (n <= LVCAP);
    if (inl)
        for (int i = tid; i < n; i += 256) cvl[i] = LOAD_COH(&cv[i]);
    if (tid == 0) { s_prefix = 0; s_kth = KTOP; s_ng = 0; s_nt = 0; }
    if (tid < KTOP) { sel_v[tid] = 0.f; sel_i[tid] = -1; }
    __syncthreads();

    if (n > KTOP) {
        for (int shift = 24; shift >= 0; shift -= 8) {
            hist[tid] = 0;
            __syncthreads();
            unsigned pref = s_prefix;
            unsigned hmask = (shift == 24) ? 0u : (0xFFFFFFFFu << (shift + 8));
            for (int i = tid; i < n; i += 256) {
                unsigned u = __float_as_uint(inl ? cvl[i] : LOAD_COH(&cv[i]));
                if ((u & hmask) == (pref & hmask))
                    atomicAdd(&hist[(u >> shift) & 255], 1);
            }
            __syncthreads();
            if (tid < 64) {   // single-wave suffix scan, lane L owns bins 4L..4L+3
                int h0 = hist[tid*4+0], h1 = hist[tid*4+1], h2 = hist[tid*4+2], h3 = hist[tid*4+3];
                int ls3 = h3, ls2 = h2 + ls3, ls1 = h1 + ls2, ls0 = h0 + ls1;
                int sum = ls0;
                for (int off = 1; off < 64; off <<= 1) {
                    int vv2 = __shfl_down(sum, off, 64);
                    if (tid + off < 64) sum += vv2;
                }
                int excl = sum - ls0;
                int kth = s_kth;
                int SS0=ls0+excl, SS1=ls1+excl, SS2=ls2+excl, SS3=ls3+excl, SS4=excl;
                unsigned pr = s_prefix;
                int bin = -1, rem = 0;
                if (SS0 >= kth && SS1 < kth) { bin = tid*4+0; rem = kth - SS1; }
                else if (SS1 >= kth && SS2 < kth) { bin = tid*4+1; rem = kth - SS2; }
                else if (SS2 >= kth && SS3 < kth) { bin = tid*4+2; rem = kth - SS3; }
                else if (SS3 >= kth && SS4 < kth) { bin = tid*4+3; rem = kth - SS4; }
                if (bin >= 0) { s_prefix = pr | ((unsigned)bin << shift); s_kth = rem; }
            }
            __syncthreads();
        }
        unsigned T = s_prefix;
        int need_eq = s_kth;
        for (int i = tid; i < n; i += 256) {
            unsigned u = __float_as_uint(inl ? cvl[i] : LOAD_COH(&cv[i]));
            if (u > T) {
                int s2 = atomicAdd(&s_ng, 1);
                if (s2 < KTOP) { sel_v[s2] = __uint_as_float(u); sel_i[s2] = LOAD_COH(&ci[i]); }
            } else if (u == T) {
                int s2 = atomicAdd(&s_nt, 1);
                if (s2 < 512) tie_i[s2] = LOAD_COH(&ci[i]);
            }
        }
        __syncthreads();
        int G = s_ng; if (G > KTOP) G = KTOP;
        int nt = s_nt; if (nt > 512) nt = 512;
        for (int t2 = tid; t2 < nt; t2 += 256) {
            int mine = tie_i[t2];
            int rank = 0;
            for (int j = 0; j < nt; ++j)
                if (tie_i[j] < mine) rank++;   // pixel indices distinct
            if (rank < need_eq && G + rank < KTOP) {
                sel_v[G + rank] = __uint_as_float(T);
                sel_i[G + rank] = mine;
            }
        }
        __syncthreads();
    } else {
        for (int i = tid; i < n; i += 256) { sel_v[i] = LOAD_COH(&cv[i]); sel_i[i] = LOAD_COH(&ci[i]); }
        __syncthreads();
    }

    // vmax = max val == global max of gauss map (peaks on integer pixels, exp(0)=1);
    // min ~ 0 within 1e-6 -> fold norm01 into log2 domain: out = 2^(lv - lvoff + d2*w)
    if (tid < 64) {
        float vmv = sel_v[tid];
        if (tid + 64 < KTOP) vmv = fmaxf(vmv, sel_v[tid + 64]);
        for (int off = 32; off > 0; off >>= 1) vmv = fmaxf(vmv, __shfl_xor(vmv, off, 64));
        if (tid == 0) s_lvoff = log2f(vmv + 1e-6f);
    }
    __syncthreads();

    if (tid < KTOP) {
        float val = sel_v[tid];
        int idx = sel_i[tid];
        float xk = 0.f, yk = 0.f, wv = -1.f, lv = -INFINITY;
        if (val > 0.f && idx >= 0) {
            yk = (float)(idx / WW);
            xk = (float)(idx % WW);
            float z = fmaxf(depth[b * HWP + idx], 1e-3f);
            float r = fminf(fmaxf(14.0f / z, 1.5f), 18.0f);
            float s2 = 0.6f * r;
            s2 = s2 * s2;
            wv = -LOG2E / (2.0f * s2 + 1e-6f);
            lv = log2f(val) - s_lvoff;
        }
        pk4g[b * KTOP + tid] = make_float4(lv, xk, yk, wv);   // kernel boundary -> gauss
    }
}

// ---- K3: per-strip (64x16) peak cull + gaussian max -> OUT, 4 px/thread -----
__global__ __launch_bounds__(256) void gauss_out_k(const float4* __restrict__ pk4g,
                                                   float* __restrict__ out) {
    int blk = blockIdx.x, tid = threadIdx.x;
    int b = blk / SPI, s = blk % SPI;
    int sy = s / SPRX, sx = s % SPRX;
    int y0 = sy * GSH, x0 = sx * GSW;
    __shared__ float4 spk[KTOP];
    __shared__ int s_c0, s_cnt;
    bool keep = false;
    float4 pk;
    if (tid < KTOP) {
        pk = pk4g[b * KTOP + tid];
        float cut = (pk.x + NLOG2TAU) / (-pk.w);   // invalid: -inf -> drop
        float rx0 = (float)x0, rx1 = (float)(x0 + GSW - 1);
        float ry0 = (float)y0, ry1 = (float)(y0 + GSH - 1);
        float cx = fminf(fmaxf(pk.y, rx0), rx1);
        float cy = fminf(fmaxf(pk.z, ry0), ry1);
        float dx = pk.y - cx, dy = pk.z - cy;
        keep = (dx * dx + dy * dy) <= cut;
    }
    int lane = tid & 63, w = tid >> 6;
    unsigned long long m = __ballot(keep);
    if (w == 0 && lane == 0) s_c0 = __popcll(m);
    __syncthreads();
    int base = (w == 0) ? 0 : s_c0;
    if (keep) spk[base + __popcll(m & ((1ULL << lane) - 1ULL))] = pk;
    if (w == 1 && lane == 0) s_cnt = s_c0 + __popcll(m);
    __syncthreads();
    int cnt = s_cnt;
    // 256 threads = 256 quads; strip is 16 quads wide x 16 rows
    int r = tid >> 4, qx = tid & 15;
    int y = y0 + r, x = x0 + qx * 4;
    float fx = (float)x, fy = (float)y;
    float m0 = 0.f, m1 = 0.f, m2 = 0.f, m3 = 0.f;
    for (int i = 0; i < cnt; ++i) {
        float4 p = spk[i];
        float dy = fy - p.z;
        float dy2 = dy * dy;
        float dx0 = fx - p.y;
        float dx1 = dx0 + 1.f, dx2 = dx0 + 2.f, dx3 = dx0 + 3.f;
        m0 = fmaxf(m0, __builtin_amdgcn_exp2f(fmaf(fmaf(dx0, dx0, dy2), p.w, p.x)));
        m1 = fmaxf(m1, __builtin_amdgcn_exp2f(fmaf(fmaf(dx1, dx1, dy2), p.w, p.x)));
        m2 = fmaxf(m2, __builtin_amdgcn_exp2f(fmaf(fmaf(dx2, dx2, dy2), p.w, p.x)));
        m3 = fmaxf(m3, __builtin_amdgcn_exp2f(fmaf(fmaf(dx3, dx3, dy2), p.w, p.x)));
    }
    *(float4*)&out[b * HWP + y * WW + x] = make_float4(m0, m1, m2, m3);
}

extern "C" void kernel_launch(void* const* d_in, const int* in_sizes, int n_in,
                              void* d_out, int out_size, void* d_ws, size_t ws_size,
                              hipStream_t stream) {
    const float* score = (const float*)d_in[0];
    const float* depth = (const float*)d_in[1];
    float* out = (float*)d_out;
    int total = in_sizes[0];       // B * H * W
    int B_ = total / HWP;          // 8

    // workspace:
    //  buf1: prod
    //  buf2: {cand_val[0:CAP] | cand_idx[CAP:2*CAP]} per batch
    //  small: pk4 | cand_cnt | done_cnt | pmm
    float* buf1 = (float*)d_ws;
    float* buf2 = buf1 + total;
    char* small = (char*)(buf2 + total);
    float4* pk4 = (float4*)small;
    int* cand_cnt = (int*)(small + B_ * KTOP * sizeof(float4));
    int* done_cnt = cand_cnt + B_ * CNT_STRIDE;
    float2* pmm = (float2*)(done_cnt + B_ * CNT_STRIDE);

    pool_fused_k<<<B_ * NTPI, 256, 0, stream>>>(score, buf1, pmm, cand_cnt, done_cnt, B_);
    cs_nms_topk_k<<<B_ * NTPI, 256, 0, stream>>>(score, buf1, pmm, buf2, cand_cnt,
                                                 done_cnt, depth, pk4);
    gauss_out_k<<<B_ * SPI, 256, 0, stream>>>(pk4, out);
}

// Round 11
// 32.243 us; speedup vs baseline: 1.3608x; 1.3608x over previous
//
#include <hip/hip_runtime.h>
#include <math.h>

#define HH 320
#define WW 320
#define HWP (HH * WW)       // pixels per batch image
#define KTOP 80
#define CNT_STRIDE 64       // pad per-batch counters to separate 256B lines
#define CAP (HWP / 2)       // max candidates kept per batch (val+idx pack one buffer)
#define LVCAP 8192          // candidates cached in LDS for topk (32KB)
#define TW 32               // pool/nms tile width
#define TH 64               // pool/nms tile height
#define NTPRX (WW / TW)     // 10 tiles per row
#define NTPI (NTPRX * (HH / TH))  // 50 tiles per image
#define GSW 64              // gauss strip width
#define GSH 16              // gauss strip height
#define SPRX (WW / GSW)     // 5 strips per row
#define SPI (SPRX * (HH / GSH))  // 100 strips per image
#define LOG2E 1.4426950408889634f
#define NLOG2TAU 19.931568569324174f   // -log2(1e-6)

__device__ __forceinline__ void wave_minmax(float& mn, float& mx) {
    for (int off = 32; off > 0; off >>= 1) {
        mn = fminf(mn, __shfl_xor(mn, off, 64));
        mx = fmaxf(mx, __shfl_xor(mx, off, 64));
    }
}

// ---- K1: fused 9x9 avg pools -> prod, per-block minmax -> pmm ---------------
__global__ __launch_bounds__(256) void pool_fused_k(
        const float* __restrict__ score, float* __restrict__ prod,
        float2* __restrict__ pmm, int* __restrict__ cand_cnt, int B_) {
    int tid = threadIdx.x;
    if (blockIdx.x == 0)
        for (int t = tid; t < B_ * CNT_STRIDE; t += 256) cand_cnt[t] = 0;
    int blk = blockIdx.x;
    int b = blk / NTPI, t = blk % NTPI;
    int ty0 = (t / NTPRX) * TH, tx0 = (t % NTPRX) * TW;
    __shared__ float rss[TH + 8][TW + 4];   // [72][36], row sums (score)
    __shared__ float rso[TH + 8][TW + 4];   // [72][36], row sums (occ)
    const float4* img4 = (const float4*)(score + b * HWP);
    // phase A: 9-tap row sums for 72 rows x 8 quads (zero-pad OOB)
    for (int i = tid; i < (TH + 8) * (TW / 4); i += 256) {
        int r = i / (TW / 4), q = i % (TW / 4);
        int gy = ty0 - 4 + r;
        float o0=0,o1=0,o2=0,o3=0,p0=0,p1=0,p2=0,p3=0;
        if (gy >= 0 && gy < HH) {
            const float4* row4 = img4 + gy * (WW / 4);
            int gq = tx0 / 4 + q;
            float4 a = (gq > 0) ? row4[gq - 1] : make_float4(0,0,0,0);
            float4 bb = row4[gq];
            float4 c = (gq < WW / 4 - 1) ? row4[gq + 1] : make_float4(0,0,0,0);
            float w0=a.x,w1=a.y,w2=a.z,w3=a.w,w4=bb.x,w5=bb.y,w6=bb.z,w7=bb.w,w8=c.x,w9=c.y,w10=c.z,w11=c.w;
            float s = w0+w1+w2+w3+w4+w5+w6+w7+w8;
            o0=s; s+=w9-w0; o1=s; s+=w10-w1; o2=s; s+=w11-w2; o3=s;
            float c0=(w0>0.2f)?1.f:0.f, c1=(w1>0.2f)?1.f:0.f, c2=(w2>0.2f)?1.f:0.f, c3=(w3>0.2f)?1.f:0.f;
            float c4=(w4>0.2f)?1.f:0.f, c5=(w5>0.2f)?1.f:0.f, c6=(w6>0.2f)?1.f:0.f, c7=(w7>0.2f)?1.f:0.f;
            float c8=(w8>0.2f)?1.f:0.f, c9=(w9>0.2f)?1.f:0.f, c10=(w10>0.2f)?1.f:0.f, c11=(w11>0.2f)?1.f:0.f;
            float u = c0+c1+c2+c3+c4+c5+c6+c7+c8;
            p0=u; u+=c9-c0; p1=u; u+=c10-c1; p2=u; u+=c11-c2; p3=u;
        }
        *(float4*)&rss[r][q * 4] = make_float4(o0,o1,o2,o3);
        *(float4*)&rso[r][q * 4] = make_float4(p0,p1,p2,p3);
    }
    __syncthreads();
    // phase B: 9-tap column sums -> prod + minmax
    float tmn = INFINITY, tmx = 0.f;
    const float inv81 = 1.0f / 81.0f;
    float4* pr4 = (float4*)(prod + b * HWP);
    for (int i = tid; i < TH * (TW / 4); i += 256) {
        int r = i / (TW / 4), q = i % (TW / 4);
        float sx=0,sy=0,sz=0,sw=0, ox=0,oy=0,oz=0,ow=0;
#pragma unroll
        for (int j = 0; j < 9; ++j) {
            float4 s = *(float4*)&rss[r + j][q * 4];
            float4 o = *(float4*)&rso[r + j][q * 4];
            sx+=s.x; sy+=s.y; sz+=s.z; sw+=s.w;
            ox+=o.x; oy+=o.y; oz+=o.z; ow+=o.w;
        }
        float px=(ox*inv81)*(sx*inv81), py=(oy*inv81)*(sy*inv81);
        float pz=(oz*inv81)*(sz*inv81), pw=(ow*inv81)*(sw*inv81);
        pr4[(ty0 + r) * (WW / 4) + tx0 / 4 + q] = make_float4(px,py,pz,pw);
        tmn = fminf(tmn, fminf(fminf(px,py), fminf(pz,pw)));
        tmx = fmaxf(tmx, fmaxf(fmaxf(px,py), fmaxf(pz,pw)));
    }
    wave_minmax(tmn, tmx);
    __shared__ float wmn[4], wmx[4];
    int w = tid >> 6;
    if ((tid & 63) == 0) { wmn[w] = tmn; wmx[w] = tmx; }
    __syncthreads();
    if (tid == 0)
        pmm[blk] = make_float2(fminf(fminf(wmn[0],wmn[1]), fminf(wmn[2],wmn[3])),
                               fmaxf(fmaxf(wmx[0],wmx[1]), fmaxf(wmx[2],wmx[3])));
}

// ---- K2: compact_score + 5x5 NMS (separable, in LDS) + compaction -----------
__global__ __launch_bounds__(256) void cs_nms_k(
        const float* __restrict__ score, const float* __restrict__ prod,
        const float2* __restrict__ pmm, float* __restrict__ cand_base,
        int* __restrict__ cand_cnt) {
    int tid = threadIdx.x;
    int blk = blockIdx.x;
    int b = blk / NTPI, t = blk % NTPI;
    int ty0 = (t / NTPRX) * TH, tx0 = (t % NTPRX) * TW;
    // reduce this batch's NTPI pmm pairs (wave 0 does the work)
    float tmn = INFINITY, tmx = 0.f;
    if (tid < NTPI) { float2 e = pmm[b * NTPI + tid]; tmn = e.x; tmx = e.y; }
    wave_minmax(tmn, tmx);
    __shared__ float s_mn, s_inv;
    if (tid == 0) { s_mn = tmn; s_inv = 1.0f / (tmx - tmn + 1e-6f); }
    __shared__ float cs[TH + 4][TW + 8 + 4];   // [68][44], col 0 <-> gx = tx0-4
    __shared__ float rm[TH + 4][TW + 4];       // [68][36], 5-tap row max
    __syncthreads();
    float mn = s_mn, inv = s_inv;
    const float4* sc4 = (const float4*)(score + b * HWP);
    const float4* pr4 = (const float4*)(prod + b * HWP);
    // phase A: cs over rows ty0-2..+65, 10 col quads (zero-pad OOB)
    for (int i = tid; i < (TH + 4) * 10; i += 256) {
        int r = i / 10, q = i % 10;
        int gy = ty0 - 2 + r;
        int gq = tx0 / 4 - 1 + q;
        float4 c4 = make_float4(0,0,0,0);
        if (gy >= 0 && gy < HH && gq >= 0 && gq < WW / 4) {
            float4 s4 = sc4[gy * (WW / 4) + gq];
            float4 p4 = pr4[gy * (WW / 4) + gq];
            c4.x = s4.x * ((p4.x - mn) * inv); c4.y = s4.y * ((p4.y - mn) * inv);
            c4.z = s4.z * ((p4.z - mn) * inv); c4.w = s4.w * ((p4.w - mn) * inv);
        }
        *(float4*)&cs[r][q * 4] = c4;
    }
    __syncthreads();
    // phase B: rm[r][x] = max cs[r][x+2 .. x+6]  (px col x <-> cs col x+4)
    for (int i = tid; i < (TH + 4) * (TW / 4); i += 256) {
        int r = i / (TW / 4), x = (i % (TW / 4)) * 4;
        float c0=cs[r][x+2], c1=cs[r][x+3], c2=cs[r][x+4], c3=cs[r][x+5];
        float c4v=cs[r][x+6], c5=cs[r][x+7], c6=cs[r][x+8], c7=cs[r][x+9];
        float m01=fmaxf(c0,c1), m23=fmaxf(c2,c3), m45=fmaxf(c4v,c5), m67=fmaxf(c6,c7);
        float r0 = fmaxf(fmaxf(m01, m23), c4v);
        float r1 = fmaxf(fmaxf(c1, m23), m45);
        float r2 = fmaxf(fmaxf(m23, m45), c6);
        float r3 = fmaxf(fmaxf(c3, m45), m67);
        *(float4*)&rm[r][x] = make_float4(r0,r1,r2,r3);
    }
    __syncthreads();
    // phase C: NMS decision, 2 quads/thread (512 quads = 2*256 exactly)
    bool cd[8]; float vv[8]; int pb[2]; int offs[8];
#pragma unroll
    for (int qq = 0; qq < 2; ++qq) {
        int quad = qq * 256 + tid;
        int r = quad >> 3, x = (quad & 7) * 4;
        float4 v = *(float4*)&cs[r + 2][x + 4];
        float4 nm = *(float4*)&rm[r][x];
#pragma unroll
        for (int k = 1; k <= 4; ++k) {
            float4 rr = *(float4*)&rm[r + k][x];
            nm.x=fmaxf(nm.x,rr.x); nm.y=fmaxf(nm.y,rr.y);
            nm.z=fmaxf(nm.z,rr.z); nm.w=fmaxf(nm.w,rr.w);
        }
        pb[qq] = (ty0 + r) * WW + tx0 + x;
        cd[qq*4+0] = v.x > 0.f && v.x >= nm.x; vv[qq*4+0] = v.x;
        cd[qq*4+1] = v.y > 0.f && v.y >= nm.y; vv[qq*4+1] = v.y;
        cd[qq*4+2] = v.z > 0.f && v.z >= nm.z; vv[qq*4+2] = v.z;
        cd[qq*4+3] = v.w > 0.f && v.w >= nm.w; vv[qq*4+3] = v.w;
    }
    int lane = tid & 63, w = tid >> 6;
    unsigned long long lower = (1ULL << lane) - 1ULL;
    int wave_run = 0;
#pragma unroll
    for (int j = 0; j < 8; ++j) {
        unsigned long long m = __ballot(cd[j]);
        offs[j] = wave_run + __popcll(m & lower);
        wave_run += __popcll(m);
    }
    __shared__ int wbase[4];
    __shared__ int blockbase;
    if (lane == 0) wbase[w] = wave_run;
    __syncthreads();
    if (tid == 0) {
        int a0=wbase[0], a1=wbase[1], a2=wbase[2], a3=wbase[3];
        int tot = a0+a1+a2+a3;
        wbase[0]=0; wbase[1]=a0; wbase[2]=a0+a1; wbase[3]=a0+a1+a2;
        blockbase = tot ? atomicAdd(&cand_cnt[b * CNT_STRIDE], tot) : 0;
    }
    __syncthreads();
    float* cv = cand_base + b * HWP;
    int* ci = (int*)(cand_base + b * HWP + CAP);
    int bb2 = blockbase + wbase[w];
#pragma unroll
    for (int j = 0; j < 8; ++j) {
        if (cd[j]) {
            int slot = bb2 + offs[j];
            if (slot < CAP) { cv[slot] = vv[j]; ci[slot] = pb[j >> 2] + (j & 3); }
        }
    }
}

// ---- K3: radix-select top-80 per batch (values LDS-cached) ------------------
__global__ __launch_bounds__(1024) void topk_k(
        const float* __restrict__ cand_base, const int* __restrict__ cand_cnt,
        const float* __restrict__ depth, float4* __restrict__ pk4g) {
    int b = blockIdx.x;
    int tid = threadIdx.x;  // 1024 threads
    int n = cand_cnt[b * CNT_STRIDE];
    if (n > CAP) n = CAP;
    const float* cv = cand_base + b * HWP;
    const int* ci = (const int*)(cand_base + b * HWP + CAP);

    __shared__ float cvl[LVCAP];
    __shared__ int hist[256];
    __shared__ unsigned s_prefix;
    __shared__ int s_kth;
    __shared__ float sel_v[KTOP];
    __shared__ int sel_i[KTOP];
    __shared__ int s_ng, s_nt;
    __shared__ int tie_i[512];
    __shared__ float s_lvoff;

    bool inl = (n <= LVCAP);
    if (inl) {
        int n4 = n >> 2;
        const float4* cv4 = (const float4*)cv;
        for (int i = tid; i < n4; i += 1024) {
            float4 v = cv4[i];
            cvl[i*4+0] = v.x; cvl[i*4+1] = v.y; cvl[i*4+2] = v.z; cvl[i*4+3] = v.w;
        }
        for (int i = n4 * 4 + tid; i < n; i += 1024) cvl[i] = cv[i];
    }
    if (tid == 0) { s_prefix = 0; s_kth = KTOP; s_ng = 0; s_nt = 0; }
    if (tid < KTOP) { sel_v[tid] = 0.f; sel_i[tid] = -1; }
    __syncthreads();

    if (n > KTOP) {
        for (int shift = 24; shift >= 0; shift -= 8) {
            if (tid < 256) hist[tid] = 0;
            __syncthreads();
            unsigned pref = s_prefix;
            unsigned hmask = (shift == 24) ? 0u : (0xFFFFFFFFu << (shift + 8));
            for (int i = tid; i < n; i += 1024) {
                unsigned u = __float_as_uint(inl ? cvl[i] : cv[i]);
                if ((u & hmask) == (pref & hmask))
                    atomicAdd(&hist[(u >> shift) & 255], 1);
            }
            __syncthreads();
            if (tid < 64) {   // single-wave suffix scan, lane L owns bins 4L..4L+3
                int h0 = hist[tid*4+0], h1 = hist[tid*4+1], h2 = hist[tid*4+2], h3 = hist[tid*4+3];
                int ls3 = h3, ls2 = h2 + ls3, ls1 = h1 + ls2, ls0 = h0 + ls1;
                int sum = ls0;
                for (int off = 1; off < 64; off <<= 1) {
                    int vv2 = __shfl_down(sum, off, 64);
                    if (tid + off < 64) sum += vv2;
                }
                int excl = sum - ls0;
                int kth = s_kth;
                int SS0=ls0+excl, SS1=ls1+excl, SS2=ls2+excl, SS3=ls3+excl, SS4=excl;
                unsigned pr = s_prefix;
                int bin = -1, rem = 0;
                if (SS0 >= kth && SS1 < kth) { bin = tid*4+0; rem = kth - SS1; }
                else if (SS1 >= kth && SS2 < kth) { bin = tid*4+1; rem = kth - SS2; }
                else if (SS2 >= kth && SS3 < kth) { bin = tid*4+2; rem = kth - SS3; }
                else if (SS3 >= kth && SS4 < kth) { bin = tid*4+3; rem = kth - SS4; }
                if (bin >= 0) { s_prefix = pr | ((unsigned)bin << shift); s_kth = rem; }
            }
            __syncthreads();
        }
        unsigned T = s_prefix;
        int need_eq = s_kth;
        for (int i = tid; i < n; i += 1024) {
            unsigned u = __float_as_uint(inl ? cvl[i] : cv[i]);
            if (u > T) {
                int s2 = atomicAdd(&s_ng, 1);
                if (s2 < KTOP) { sel_v[s2] = __uint_as_float(u); sel_i[s2] = ci[i]; }
            } else if (u == T) {
                int s2 = atomicAdd(&s_nt, 1);
                if (s2 < 512) tie_i[s2] = ci[i];
            }
        }
        __syncthreads();
        int G = s_ng; if (G > KTOP) G = KTOP;
        int nt = s_nt; if (nt > 512) nt = 512;
        for (int t2 = tid; t2 < nt; t2 += 1024) {
            int mine = tie_i[t2];
            int rank = 0;
            for (int j = 0; j < nt; ++j)
                if (tie_i[j] < mine) rank++;   // pixel indices distinct
            if (rank < need_eq && G + rank < KTOP) {
                sel_v[G + rank] = __uint_as_float(T);
                sel_i[G + rank] = mine;
            }
        }
        __syncthreads();
    } else {
        for (int i = tid; i < n; i += 1024) { sel_v[i] = cv[i]; sel_i[i] = ci[i]; }
        __syncthreads();
    }

    // vmax = max val == global max of gauss map (peaks on integer pixels, exp(0)=1);
    // min ~ 0 within 1e-6 -> fold norm01 into log2 domain: out = 2^(lv - lvoff + d2*w)
    if (tid < 64) {
        float vmv = sel_v[tid];
        if (tid + 64 < KTOP) vmv = fmaxf(vmv, sel_v[tid + 64]);
        for (int off = 32; off > 0; off >>= 1) vmv = fmaxf(vmv, __shfl_xor(vmv, off, 64));
        if (tid == 0) s_lvoff = log2f(vmv + 1e-6f);
    }
    __syncthreads();

    if (tid < KTOP) {
        float val = sel_v[tid];
        int idx = sel_i[tid];
        float xk = 0.f, yk = 0.f, wv = -1.f, lv = -INFINITY;
        if (val > 0.f && idx >= 0) {
            yk = (float)(idx / WW);
            xk = (float)(idx % WW);
            float z = fmaxf(depth[b * HWP + idx], 1e-3f);
            float r = fminf(fmaxf(14.0f / z, 1.5f), 18.0f);
            float s2 = 0.6f * r;
            s2 = s2 * s2;
            wv = -LOG2E / (2.0f * s2 + 1e-6f);
            lv = log2f(val) - s_lvoff;
        }
        pk4g[b * KTOP + tid] = make_float4(lv, xk, yk, wv);
    }
}

// ---- K4: per-strip (64x16) peak cull + gaussian max -> OUT, 4 px/thread -----
__global__ __launch_bounds__(256) void gauss_out_k(const float4* __restrict__ pk4g,
                                                   float* __restrict__ out) {
    int blk = blockIdx.x, tid = threadIdx.x;
    int b = blk / SPI, s = blk % SPI;
    int sy = s / SPRX, sx = s % SPRX;
    int y0 = sy * GSH, x0 = sx * GSW;
    __shared__ float4 spk[KTOP];
    __shared__ int s_c0, s_cnt;
    bool keep = false;
    float4 pk;
    if (tid < KTOP) {
        pk = pk4g[b * KTOP + tid];
        float cut = (pk.x + NLOG2TAU) / (-pk.w);   // invalid: -inf -> drop
        float rx0 = (float)x0, rx1 = (float)(x0 + GSW - 1);
        float ry0 = (float)y0, ry1 = (float)(y0 + GSH - 1);
        float cx = fminf(fmaxf(pk.y, rx0), rx1);
        float cy = fminf(fmaxf(pk.z, ry0), ry1);
        float dx = pk.y - cx, dy = pk.z - cy;
        keep = (dx * dx + dy * dy) <= cut;
    }
    int lane = tid & 63, w = tid >> 6;
    unsigned long long m = __ballot(keep);
    if (w == 0 && lane == 0) s_c0 = __popcll(m);
    __syncthreads();
    int base = (w == 0) ? 0 : s_c0;
    if (keep) spk[base + __popcll(m & ((1ULL << lane) - 1ULL))] = pk;
    if (w == 1 && lane == 0) s_cnt = s_c0 + __popcll(m);
    __syncthreads();
    int cnt = s_cnt;
    // 256 threads = 256 quads; strip is 16 quads wide x 16 rows
    int r = tid >> 4, qx = tid & 15;
    int y = y0 + r, x = x0 + qx * 4;
    float fx = (float)x, fy = (float)y;
    float m0 = 0.f, m1 = 0.f, m2 = 0.f, m3 = 0.f;
    for (int i = 0; i < cnt; ++i) {
        float4 p = spk[i];
        float dy = fy - p.z;
        float dy2 = dy * dy;
        float dx0 = fx - p.y;
        float dx1 = dx0 + 1.f, dx2 = dx0 + 2.f, dx3 = dx0 + 3.f;
        m0 = fmaxf(m0, __builtin_amdgcn_exp2f(fmaf(fmaf(dx0, dx0, dy2), p.w, p.x)));
        m1 = fmaxf(m1, __builtin_amdgcn_exp2f(fmaf(fmaf(dx1, dx1, dy2), p.w, p.x)));
        m2 = fmaxf(m2, __builtin_amdgcn_exp2f(fmaf(fmaf(dx2, dx2, dy2), p.w, p.x)));
        m3 = fmaxf(m3, __builtin_amdgcn_exp2f(fmaf(fmaf(dx3, dx3, dy2), p.w, p.x)));
    }
    *(float4*)&out[b * HWP + y * WW + x] = make_float4(m0, m1, m2, m3);
}

extern "C" void kernel_launch(void* const* d_in, const int* in_sizes, int n_in,
                              void* d_out, int out_size, void* d_ws, size_t ws_size,
                              hipStream_t stream) {
    const float* score = (const float*)d_in[0];
    const float* depth = (const float*)d_in[1];
    float* out = (float*)d_out;
    int total = in_sizes[0];       // B * H * W
    int B_ = total / HWP;          // 8

    // workspace:
    //  buf1: prod
    //  buf2: {cand_val[0:CAP] | cand_idx[CAP:2*CAP]} per batch
    //  small: pk4 | cand_cnt | pmm
    float* buf1 = (float*)d_ws;
    float* buf2 = buf1 + total;
    char* small = (char*)(buf2 + total);
    float4* pk4 = (float4*)small;
    int* cand_cnt = (int*)(small + B_ * KTOP * sizeof(float4));
    float2* pmm = (float2*)(cand_cnt + B_ * CNT_STRIDE);

    pool_fused_k<<<B_ * NTPI, 256, 0, stream>>>(score, buf1, pmm, cand_cnt, B_);
    cs_nms_k<<<B_ * NTPI, 256, 0, stream>>>(score, buf1, pmm, buf2, cand_cnt);
    topk_k<<<B_, 1024, 0, stream>>>(buf2, cand_cnt, depth, pk4);
    gauss_out_k<<<B_ * SPI, 256, 0, stream>>>(pk4, out);
}